// Round 10
// baseline (17.838 us; speedup 1.0000x reference)
//
#include <hip/hip_runtime.h>
#include <hip/hip_bf16.h>

#define T_LEN  4096
#define NLAG   5
#define CMAX   575               // max lag covered (NLAG-1)*128 + 63
#define ESTR   712               // per-copy stride (bf16 elems), mult of 8
#define ROUNDS 9                 // 9 rounds x 8 lags = 72 lags per wave

typedef __attribute__((ext_vector_type(8))) short short8;
typedef __attribute__((ext_vector_type(4))) float f32x4;

static __device__ __forceinline__ unsigned short f2bf(float f) {
  __hip_bfloat16 h = __float2bfloat16(f);
  return *reinterpret_cast<unsigned short*>(&h);
}

// Single launch, barrier-free GEMM loop.
// Prologue: k_d (d=0..575) via per-mode complex recurrence (lane=mode),
// stored as 8 shifted bf16 copies of reversed-k E[y]=k_{CMAX-y} in LDS.
// Main loop: each of 8 waves owns a 16x32 output slice; A-fragments are
// loaded DIRECTLY from global u (2 float4/lane) and cvt'd in-register;
// B-fragments are aligned ds_read_b128 from E8 (copy p=(7-(lc16&7))).
// No LDS A-tile, no ds_write, no __syncthreads after E8 is published.
__global__ __launch_bounds__(512, 2) void ssm_one(
    const float* __restrict__ u, const float* __restrict__ rho,
    const float* __restrict__ theta, const float* __restrict__ br,
    const float* __restrict__ bi, const float* __restrict__ cr,
    const float* __restrict__ ci, float* __restrict__ out) {
  __shared__ __align__(16) unsigned short E8[8 * ESTR];   // 11.1 KB rev-k copies
  __shared__ __align__(16) float pad[8][8][68];           // 17.4 KB reduce pad

  const int tid = threadIdx.x;
  const int lane = tid & 63;
  const int w = tid >> 6;                 // 0..7
  const int q = w >> 1, h = w & 1;        // row-quarter, col-half

  const int bid = blockIdx.x;             // 256 % 8 == 0 -> bijective XCD swizzle
  const int swz = (bid & 7) * 32 + (bid >> 3);
  const int t0 = (swz & 63) * 64;
  const int b0 = (swz >> 6) * 64;

  const int lrow = lane >> 4, lc16 = lane & 15;
  const float4 z4 = make_float4(0.f, 0.f, 0.f, 0.f);

  const float* ubase = u + (size_t)(b0 + q * 16 + lc16) * T_LEN;

  float4 av[2][4][2];                     // [slot][ks][lo/hi]
  f32x4 acc[2] = {};

  // A-fragment cols for (j, ks): gg = t0 - 128j + ks*32 + lrow*8, 8 floats
#define LOADA(j, S) { _Pragma("unroll") for (int ks_ = 0; ks_ < 4; ++ks_) {       \
    const int gg = t0 - (j) * 128 + ks_ * 32 + lrow * 8;                          \
    const bool ok_ = (unsigned)gg < 4096u;   /* gg%8==0 -> covers gg..gg+7 */     \
    const float* p_ = ubase + (ok_ ? gg : 0);                                     \
    float4 v0_ = *reinterpret_cast<const float4*>(p_);                            \
    float4 v1_ = *reinterpret_cast<const float4*>(p_ + 4);                        \
    if (!ok_) { v0_ = z4; v1_ = z4; }                                             \
    av[S][ks_][0] = v0_; av[S][ks_][1] = v1_; } }

#define CVTAF(S) { _Pragma("unroll") for (int ks_ = 0; ks_ < 4; ++ks_) {          \
    const float4 a_ = av[S][ks_][0], b_ = av[S][ks_][1];                          \
    short8 v_;                                                                    \
    v_[0] = (short)f2bf(a_.x); v_[1] = (short)f2bf(a_.y);                         \
    v_[2] = (short)f2bf(a_.z); v_[3] = (short)f2bf(a_.w);                         \
    v_[4] = (short)f2bf(b_.x); v_[5] = (short)f2bf(b_.y);                         \
    v_[6] = (short)f2bf(b_.z); v_[7] = (short)f2bf(b_.w);                         \
    af[ks_] = v_; } }

  LOADA(0, 0);                            // first-touch misses hide under d-eval

  // ---- zero E8 (unwritten slots / tails must read 0) ----
  {
    const short8 z8 = {};
    for (int c = tid; c < ESTR; c += 512)
      *reinterpret_cast<short8*>(&E8[c * 8]) = z8;
  }

  // ---- per-mode params (lane = mode), lambda powers 0..8 ----
  const float rh = rho[lane], th = theta[lane];
  const float lr2 = -1.4426950408f * log1pf(expf(rh));       // log2 r
  const float rr_ = exp2f(lr2);
  const float lre = rr_ * __cosf(th), lim = rr_ * __sinf(th);
  const float brv = br[lane], biv = bi[lane];
  const float crv = cr[lane], civ = ci[lane];
  const float wre = crv * brv + civ * biv;                   // conj(c)*b
  const float wim = crv * biv - civ * brv;

  float Lr[9], Li[9];
  Lr[0] = 1.f; Li[0] = 0.f;
#pragma unroll
  for (int i = 1; i <= 8; ++i) {
    Lr[i] = Lr[i - 1] * lre - Li[i - 1] * lim;
    Li[i] = Lr[i - 1] * lim + Li[i - 1] * lre;
  }

  // g = conj(c)b * lam^(72w): wave w owns lags 72w .. 72w+71
  const float d0f = (float)(8 * ROUNDS * w);
  const float rd0 = exp2f(d0f * lr2);
  float f0 = d0f * (th * 0.15915494309f);
  f0 -= floorf(f0);
  const float a0 = 6.2831853072f * f0;
  const float c0 = __cosf(a0), s0 = __sinf(a0);
  float gr = rd0 * (wre * c0 - wim * s0);
  float gi = rd0 * (wre * s0 + wim * c0);

  __syncthreads();                        // E8 zeros visible before stores

  // ---- d-eval: 8 independent products/round, serial lam^8 advance ----
  {
    float* mypad = &pad[w][0][0];
    const int r2 = lane >> 3, cc = lane & 7;
    for (int rnd = 0; rnd < ROUNDS; ++rnd) {
#pragma unroll
      for (int i2 = 0; i2 < 8; ++i2)
        mypad[i2 * 68 + lane] = gr * Lr[i2] - gi * Li[i2];   // Re(g * lam^i2)
      const float ngr = gr * Lr[8] - gi * Li[8];
      const float ngi = gr * Li[8] + gi * Lr[8];
      gr = ngr; gi = ngi;
      const float4 p0 = *reinterpret_cast<const float4*>(&mypad[r2 * 68 + cc * 8]);
      const float4 p1 = *reinterpret_cast<const float4*>(&mypad[r2 * 68 + cc * 8 + 4]);
      float s_ = ((p0.x + p0.y) + (p0.z + p0.w)) + ((p1.x + p1.y) + (p1.z + p1.w));
      s_ += __shfl_xor(s_, 1); s_ += __shfl_xor(s_, 2); s_ += __shfl_xor(s_, 4);
      // lane (r2,cc) holds k_d, d = 72w + 8rnd + r2; store copy cc at [y-cc]
      const int y_ = CMAX - (8 * ROUNDS * w + rnd * 8 + r2);
      if (y_ >= cc) E8[cc * ESTR + (y_ - cc)] = f2bf(s_);
    }
  }

  LOADA(1, 1);
  __syncthreads();                        // E8 complete; last barrier

  // ---- barrier-free GEMM: 5 j-iterations, 2-deep A prefetch ----
  const int pB = 7 - (lc16 & 7);
#pragma unroll
  for (int j = 0; j < NLAG; ++j) {
    short8 af[4];
    CVTAF(j & 1);
    if (j + 2 < NLAG) LOADA(j + 2, j & 1);
#pragma unroll
    for (int ks = 0; ks < 4; ++ks) {
      short8 bfr[2];
#pragma unroll
      for (int fn = 0; fn < 2; ++fn) {
        const int rB = h * 32 + fn * 16 + lc16;
        const int x0 = CMAX - j * 128 - rB + ks * 32 + lrow * 8 - pB;  // >= 0
        bfr[fn] = *reinterpret_cast<const short8*>(&E8[pB * ESTR + x0]);
      }
#pragma unroll
      for (int fn = 0; fn < 2; ++fn)
        acc[fn] = __builtin_amdgcn_mfma_f32_16x16x32_bf16(
            af[ks], bfr[fn], acc[fn], 0, 0, 0);
    }
  }

  // ---- epilogue: each wave owns rows [b0+16q, +16), cols [t0+32h, +32) ----
#pragma unroll
  for (int fn = 0; fn < 2; ++fn)
#pragma unroll
    for (int rg = 0; rg < 4; ++rg) {
      const int row = b0 + q * 16 + lrow * 4 + rg;
      const int col = t0 + h * 32 + fn * 16 + lc16;
      out[(size_t)row * T_LEN + col] = acc[fn][rg];
    }
#undef LOADA
#undef CVTAF
}

extern "C" void kernel_launch(void* const* d_in, const int* in_sizes, int n_in,
                              void* d_out, int out_size, void* d_ws, size_t ws_size,
                              hipStream_t stream) {
  const float* u     = (const float*)d_in[0];
  const float* rho   = (const float*)d_in[1];
  const float* theta = (const float*)d_in[2];
  const float* br    = (const float*)d_in[3];
  const float* bi    = (const float*)d_in[4];
  const float* cr    = (const float*)d_in[5];
  const float* ci    = (const float*)d_in[6];
  float* out = (float*)d_out;

  ssm_one<<<256, 512, 0, stream>>>(u, rho, theta, br, bi, cr, ci, out);
}

// Round 13
// 12.990 us; speedup vs baseline: 1.3732x; 1.3732x over previous
//
#include <hip/hip_runtime.h>
#include <hip/hip_bf16.h>

#define T_LEN  4096
#define NLAG   5
#define CMAX   575               // max lag covered (NLAG-1)*128 + 63
#define ESTR   728               // per-copy stride (bf16 elems), mult of 8
#define ROUNDS 9                 // 9 rounds x 8 lags = 72 lags per wave

typedef __attribute__((ext_vector_type(8))) short short8;
typedef __attribute__((ext_vector_type(4))) float f32x4;

static __device__ __forceinline__ unsigned short f2bf(float f) {
  __hip_bfloat16 h = __float2bfloat16(f);
  return *reinterpret_cast<unsigned short*>(&h);
}

template <int CTRL>
static __device__ __forceinline__ float dppmov(float x) {
  return __int_as_float(__builtin_amdgcn_update_dpp(
      0, __float_as_int(x), CTRL, 0xF, 0xF, true));
}

#define CVT8(dst, va, vb) {                                                       \
    short8 _v;                                                                    \
    _v[0] = (short)f2bf((va).x); _v[1] = (short)f2bf((va).y);                     \
    _v[2] = (short)f2bf((va).z); _v[3] = (short)f2bf((va).w);                     \
    _v[4] = (short)f2bf((vb).x); _v[5] = (short)f2bf((vb).y);                     \
    _v[6] = (short)f2bf((vb).z); _v[7] = (short)f2bf((vb).w);                     \
    *reinterpret_cast<short8*>(dst) = _v; }

// lgkm-only barrier: drains LDS ops but lets global loads stay in flight (T4)
#define LBAR() { asm volatile("s_waitcnt lgkmcnt(0)" ::: "memory");               \
                 __builtin_amdgcn_s_barrier(); }

// Single launch. Waves 0-3: GEMM consumers; waves 4-7: A-staging producers.
// d-eval: per-mode complex recurrence (lane=mode); transpose-reduce does the
// "distribution" bits {0,1,3} as DPP split-streams (VALU) and the remaining
// reduction bits {2,4,5} as known-good __shfl_xor adds. 4 LDS ops/round.
__global__ __launch_bounds__(512) void ssm_one(
    const float* __restrict__ u, const float* __restrict__ rho,
    const float* __restrict__ theta, const float* __restrict__ br,
    const float* __restrict__ bi, const float* __restrict__ cr,
    const float* __restrict__ ci, float* __restrict__ out) {
  __shared__ __align__(16) unsigned short Ab[2][8192];     // 32 KB A dbuf
  __shared__ __align__(16) unsigned short E8[8 * ESTR];    // 11.4 KB rev-k copies

  const int tid = threadIdx.x;
  const int lane = tid & 63;
  const int w = tid >> 6;                 // 0..7
  const bool prod = (w >= 4);
  const int pt = tid & 255;

  const int bid = blockIdx.x;             // 256 % 8 == 0 -> bijective XCD swizzle
  const int swz = (bid & 7) * 32 + (bid >> 3);
  const int t0 = (swz & 63) * 64;
  const int b0 = (swz >> 6) * 64;

  const int lrow = lane >> 4, lc16 = lane & 15;
  const float4 z4 = make_float4(0.f, 0.f, 0.f, 0.f);
  float4 av[2][4][2];
  f32x4 acc[2][2] = {};

#define ISSUEA(j, S) { _Pragma("unroll") for (int h_ = 0; h_ < 4; ++h_) {         \
    const int hh = pt + 256 * h_;                                                 \
    const int r_ = hh >> 4, cg = hh & 15;                                         \
    const int gg = t0 - (j) * 128 + cg * 8;                                       \
    if ((unsigned)gg < 4096u) {                                                   \
      const float* p_ = u + (size_t)(b0 + r_) * T_LEN + gg;                       \
      av[S][h_][0] = *reinterpret_cast<const float4*>(p_);                        \
      av[S][h_][1] = *reinterpret_cast<const float4*>(p_ + 4);                    \
    } else { av[S][h_][0] = z4; av[S][h_][1] = z4; } } }

#define WRITEA(buf, S) { _Pragma("unroll") for (int h_ = 0; h_ < 4; ++h_) {       \
    const int hh = pt + 256 * h_;                                                 \
    const int r_ = hh >> 4, cg = hh & 15;                                         \
    const int eo = r_ * 128 + ((cg * 8) ^ ((r_ & 7) << 3));                       \
    CVT8(&Ab[buf][eo], av[S][h_][0], av[S][h_][1]); } }

  if (prod) ISSUEA(0, 0);                 // first-touch misses hide under d-eval

  // ---- zero E8 (x > written range must read 0: negative-lag band + tail) ----
  {
    const short8 z8 = {};
    for (int c = tid; c < ESTR; c += 512)
      *reinterpret_cast<short8*>(&E8[c * 8]) = z8;
  }

  // ---- per-mode params (lane = mode), lambda powers 0..8 ----
  const float rh = rho[lane], th = theta[lane];
  const float lr2 = -1.4426950408f * log1pf(expf(rh));       // log2 r
  const float rr_ = exp2f(lr2);
  const float lre = rr_ * __cosf(th), lim = rr_ * __sinf(th);
  const float brv = br[lane], biv = bi[lane];
  const float crv = cr[lane], civ = ci[lane];
  const float wre = crv * brv + civ * biv;                   // conj(c)*b
  const float wim = crv * biv - civ * brv;

  float Lr[9], Li[9];
  Lr[0] = 1.f; Li[0] = 0.f;
#pragma unroll
  for (int i = 1; i <= 8; ++i) {
    Lr[i] = Lr[i - 1] * lre - Li[i - 1] * lim;
    Li[i] = Lr[i - 1] * lim + Li[i - 1] * lre;
  }

  // g = conj(c)b * lam^(72w): wave w owns lags 72w .. 72w+71
  const float d0f = (float)(8 * ROUNDS * w);
  const float rd0 = exp2f(d0f * lr2);
  float f0 = d0f * (th * 0.15915494309f);
  f0 -= floorf(f0);
  const float a0 = 6.2831853072f * f0;
  const float c0 = __cosf(a0), s0 = __sinf(a0);
  float gr = rd0 * (wre * c0 - wim * s0);
  float gi = rd0 * (wre * s0 + wim * c0);

  // split-stream butterfly lane roles (lane bits 0,1,3 pick the value index;
  // bits 2,4,5 pick the E8 copy this lane writes)
  const bool l0 = lane & 1, l1 = lane & 2, l3 = lane & 8;
  const int sig = ((lane & 1) << 2) | (lane & 2) | ((lane >> 3) & 1);
  const int cc  = ((lane >> 2) & 1) | ((lane >> 3) & 2) | ((lane >> 3) & 4);

  LBAR();                                 // E8 zeros complete

  // ---- d-eval: DPP split-streams + shfl_xor reduce, 4 LDS instrs/round ----
  for (int rnd = 0; rnd < ROUNDS; ++rnd) {
    float v[8];
#pragma unroll
    for (int i2 = 0; i2 < 8; ++i2)
      v[i2] = gr * Lr[i2] - gi * Li[i2];                     // Re(g * lam^i2)
    { const float ngr = gr * Lr[8] - gi * Li[8];
      const float ngi = gr * Li[8] + gi * Lr[8];
      gr = ngr; gi = ngi; }
    // split on xor1 (value bit2 = lane bit0), quad_perm [1,0,3,2]
    float s4[4];
#pragma unroll
    for (int i = 0; i < 4; ++i) {
      const float t = l0 ? v[i + 4] : v[i];
      const float u2 = l0 ? v[i] : v[i + 4];
      s4[i] = t + dppmov<0xB1>(u2);
    }
    // split on xor2 (value bit1 = lane bit1), quad_perm [2,3,0,1]
    float s2[2];
#pragma unroll
    for (int i = 0; i < 2; ++i) {
      const float t = l1 ? s4[i + 2] : s4[i];
      const float u2 = l1 ? s4[i] : s4[i + 2];
      s2[i] = t + dppmov<0x4E>(u2);
    }
    // split on xor8 (value bit0 = lane bit3), row_ror:8
    float y;
    { const float t = l3 ? s2[1] : s2[0];
      const float u2 = l3 ? s2[0] : s2[1];
      y = t + dppmov<0x128>(u2); }
    // full reduce over lane bits 2,4,5 (known-good primitive)
    y += __shfl_xor(y, 4);
    y += __shfl_xor(y, 16);
    y += __shfl_xor(y, 32);
    // lane holds k_d, d = 72w + 8rnd + sig; write copy cc at [yy - cc]
    const int d = 72 * w + 8 * rnd + sig;
    const int yy = CMAX - d;
    if (yy >= cc) E8[cc * ESTR + (yy - cc)] = f2bf(y);
  }

  if (prod) { WRITEA(0, 0); ISSUEA(1, 1); }
  LBAR();                                 // E8 + Ab[0] ready; ISSUEA(1) in flight

#define COMPUTE(jj, buf) {                                                        \
    const unsigned short* A = Ab[buf];                                            \
    const int wm = w >> 1, wn = w & 1;                                            \
    const int pB = 7 - (lc16 & 7);                                                \
    _Pragma("unroll") for (int ks = 0; ks < 4; ++ks) {                            \
      short8 af[2], bfr[2];                                                       \
      _Pragma("unroll") for (int ft = 0; ft < 2; ++ft) {                          \
        const int r = wm * 32 + ft * 16 + lc16;                                   \
        const int pe = (ks * 32 + lrow * 8) ^ ((r & 7) << 3);                     \
        af[ft] = *reinterpret_cast<const short8*>(&A[r * 128 + pe]); }            \
      _Pragma("unroll") for (int fn = 0; fn < 2; ++fn) {                          \
        const int rB = wn * 32 + fn * 16 + lc16;                                  \
        const int x0 = CMAX - (jj) * 128 - rB + ks * 32 + lrow * 8 - pB;          \
        bfr[fn] = *reinterpret_cast<const short8*>(&E8[pB * ESTR + x0]); }        \
      _Pragma("unroll") for (int ft = 0; ft < 2; ++ft)                            \
        _Pragma("unroll") for (int fn = 0; fn < 2; ++fn)                          \
          acc[ft][fn] = __builtin_amdgcn_mfma_f32_16x16x32_bf16(                  \
              af[ft], bfr[fn], acc[ft][fn], 0, 0, 0); } }

  // ---- pipeline: consumers compute buf j&1; producers fill buf (j+1)&1.
  // LBAR (not __syncthreads) keeps ISSUEA(j+2)'s global loads in flight. ----
#pragma unroll
  for (int j = 0; j < NLAG; ++j) {
    if (prod) {
      if (j + 1 < NLAG) WRITEA((j + 1) & 1, (j + 1) & 1);
      if (j + 2 < NLAG) ISSUEA(j + 2, j & 1);
    } else {
      COMPUTE(j, j & 1);
    }
    if (j < NLAG - 1) LBAR();
  }

  // ---- epilogue (consumers only) ----
  if (!prod) {
    const int wm = w >> 1, wn = w & 1;
#pragma unroll
    for (int ft = 0; ft < 2; ++ft)
#pragma unroll
      for (int fn = 0; fn < 2; ++fn)
#pragma unroll
        for (int rg = 0; rg < 4; ++rg) {
          const int row = b0 + wm * 32 + ft * 16 + lrow * 4 + rg;
          const int col = t0 + wn * 32 + fn * 16 + lc16;
          out[(size_t)row * T_LEN + col] = acc[ft][fn][rg];
        }
  }
#undef ISSUEA
#undef WRITEA
#undef COMPUTE
}

extern "C" void kernel_launch(void* const* d_in, const int* in_sizes, int n_in,
                              void* d_out, int out_size, void* d_ws, size_t ws_size,
                              hipStream_t stream) {
  const float* u     = (const float*)d_in[0];
  const float* rho   = (const float*)d_in[1];
  const float* theta = (const float*)d_in[2];
  const float* br    = (const float*)d_in[3];
  const float* bi    = (const float*)d_in[4];
  const float* cr    = (const float*)d_in[5];
  const float* ci    = (const float*)d_in[6];
  float* out = (float*)d_out;

  ssm_one<<<256, 512, 0, stream>>>(u, rho, theta, br, bi, cr, ci, out);
}